// Round 4
// baseline (281.113 us; speedup 1.0000x reference)
//
#include <hip/hip_runtime.h>
#include <stdint.h>

#define BPU    5
#define NBINS  200
#define GLEN   195   // NBINS - BPU
#define HLEN   196   // NBINS - BPU + 1
#define KH     256   // raw key-histogram bins; key = floor(x*5) + 128
#define NCOPY  16    // rotated LDS histogram copies (16 KB LDS -> 8 blocks/CU)
#define HGRID  2048  // k_hist grid
#define MBLK   256   // merge blocks
#define LGRID  2048  // k_loss grid
#define TILE   2048  // float4 per tile = 32 KB contiguous per block-tile

// ---------------- kernel 1: histogram into private per-block slices ----------
// Lane-rotated LDS copies: copy c stores key k at slot ((k + c) & 255);
// bank = (k + c) % 32 spreads same-bin lanes across banks.

__device__ inline void bump(float v, uint32_t* __restrict__ lh, int off, int cbase) {
    int b = __float2int_rd(v * 5.0f);            // floor(5x)
    b = min(max(b, -128), 127);                  // slot in [0,255]
    atomicAdd(&lh[cbase | ((b + off) & 255)], 1u);
}

__global__ __launch_bounds__(256) void k_hist(const float4* __restrict__ x4, int n4,
                                              const float* __restrict__ x, int n,
                                              uint32_t* __restrict__ slices) {
    __shared__ uint32_t lh[NCOPY * KH];          // 16 KB
    const int t = threadIdx.x;
    const int c = t & (NCOPY - 1);
    const int cbase = c << 8;
    const int off = 128 + c;                     // key offset + rotation
    for (int j = t; j < NCOPY * KH; j += 256) lh[j] = 0u;
    __syncthreads();

    const int ntiles = n4 / TILE;
    for (int tile = blockIdx.x; tile < ntiles; tile += HGRID) {
        const int base = tile * TILE + t;
        float4 v[8];                             // 8 loads in flight / thread
        #pragma unroll
        for (int u = 0; u < 8; ++u) v[u] = x4[base + (u << 8)];
        #pragma unroll
        for (int u = 0; u < 8; ++u) {
            bump(v[u].x, lh, off, cbase); bump(v[u].y, lh, off, cbase);
            bump(v[u].z, lh, off, cbase); bump(v[u].w, lh, off, cbase);
        }
    }
    // remainder float4s (none for this shape)
    for (int i = ntiles * TILE + blockIdx.x * 256 + t; i < n4; i += HGRID * 256) {
        float4 v = x4[i];
        bump(v.x, lh, off, cbase); bump(v.y, lh, off, cbase);
        bump(v.z, lh, off, cbase); bump(v.w, lh, off, cbase);
    }
    if (blockIdx.x == 0 && t == 0)               // scalar tail (none here)
        for (int i = n4 * 4; i < n; ++i) bump(x[i], lh, off, cbase);
    __syncthreads();

    // merge 16 rotated copies; plain coalesced store to this block's slice
    uint32_t s = 0;
    #pragma unroll 4
    for (int cc = 0; cc < NCOPY; ++cc) s += lh[(cc << 8) | ((t + cc) & 255)];
    slices[(blockIdx.x << 8) | t] = s;
}

// ---------------- kernel 2: 2048 slices -> 256 partials ----------------------

__global__ __launch_bounds__(256) void k_merge(const uint32_t* __restrict__ slices,
                                               uint32_t* __restrict__ partial) {
    const int t = threadIdx.x;
    const int b = blockIdx.x;
    const int per = HGRID / MBLK;                // 8
    uint32_t s = 0;
    #pragma unroll
    for (int j = 0; j < per; ++j) s += slices[((b * per + j) << 8) | t];
    partial[(b << 8) | t] = s;
}

// ---------------- kernel 3: final sum; derive vmin; build A/B table ----------

__global__ __launch_bounds__(256) void k_tables(const uint32_t* __restrict__ partial,
                                                float2* __restrict__ gAB,
                                                float*  __restrict__ off5_out,
                                                double* __restrict__ acc,
                                                uint32_t* __restrict__ done,
                                                float inv_n) {
    __shared__ float cnt[KH];
    __shared__ float hist[NBINS];
    __shared__ float ha[HLEN];
    __shared__ int s_k0;
    const int t = threadIdx.x;
    uint32_t cv = 0;
    #pragma unroll 8
    for (int b = 0; b < MBLK; ++b) cv += partial[(b << 8) | t];
    cnt[t] = (float)cv;
    if (t == 0) s_k0 = KH;
    __syncthreads();
    if (cv) atomicMin(&s_k0, t);                 // lowest nonempty key
    __syncthreads();

    // floor(min) = floordiv(k0 - 128, 5)  (exact: bins align with integers)
    int a = s_k0 - 128;
    int fd = (a >= 0) ? (a / 5) : -((-a + 4) / 5);
    int ivmin = fd - 1;                          // vmin = floor(min) - 1
    int base = 128 + 5 * ivmin;                  // key of reference bin 0

    if (t < NBINS) {
        float h = 0.0f;
        if (t == 0) {
            for (int kk = 0; kk < KH && kk <= base; ++kk) h += cnt[kk];
        } else if (t == NBINS - 1) {
            int lo = base + (NBINS - 1); if (lo < 0) lo = 0;
            for (int kk = lo; kk < KH; ++kk) h += cnt[kk];
        } else {
            int kk = base + t;
            if (kk >= 0 && kk < KH) h = cnt[kk];
        }
        hist[t] = h * inv_n;
    }
    __syncthreads();

    // inclusive Hillis-Steele scan over hist[0..199]
    for (int offs = 1; offs < NBINS; offs <<= 1) {
        float v = 0.0f;
        if (t < NBINS && t >= offs) v = hist[t - offs];
        __syncthreads();
        if (t < NBINS && t >= offs) hist[t] += v;
        __syncthreads();
    }

    if (t < HLEN) {
        float c_lo = (t == 0) ? 0.0f : hist[t - 1];
        ha[t] = hist[t + BPU - 1] - c_lo;        // c[t+5] - c[t]
    }
    __syncthreads();

    float vmn = (float)ivmin + 0.5f;             // vmin_new
    if (t < GLEN) {
        float A = (ha[t + 1] - ha[t]) * 5.0f;    // g[t]
        float left = vmn + (float)t * 0.2f;
        float B = ha[t] - left * A + 1e-8f;      // nloss = fma(x, A, B)
        gAB[t] = make_float2(A, B);
    }
    if (t == 0) { *off5_out = vmn * 5.0f; *acc = 0.0; *done = 0u; }
}

// ---------------- kernel 4: per-element loss; last block finalizes -----------

__device__ inline float el(float v, float off5, const float2* __restrict__ sAB) {
    float fi = fminf(fmaxf(fmaf(v, 5.0f, -off5), 0.0f), (float)(GLEN - 1));
    float2 ab = sAB[(int)fi];                    // ds_read_b64 gather
    return __log2f(fmaf(v, ab.x, ab.y));
}

__global__ __launch_bounds__(256) void k_loss(const float4* __restrict__ x4, int n4,
                                              const float* __restrict__ x, int n,
                                              const float2* __restrict__ gAB,
                                              const float*  __restrict__ off5_p,
                                              double* __restrict__ acc,
                                              uint32_t* __restrict__ done,
                                              float* __restrict__ out, double inv_n) {
    __shared__ float2 sAB[GLEN];
    const int t = threadIdx.x;
    if (t < GLEN) sAB[t] = gAB[t];
    const float off5 = *off5_p;
    __syncthreads();

    float s0 = 0.f, s1 = 0.f, s2 = 0.f, s3 = 0.f;
    const int ntiles = n4 / TILE;
    for (int tile = blockIdx.x; tile < ntiles; tile += LGRID) {
        const int base = tile * TILE + t;
        float4 v[8];                             // 8 loads in flight / thread
        #pragma unroll
        for (int u = 0; u < 8; ++u) v[u] = x4[base + (u << 8)];
        #pragma unroll
        for (int u = 0; u < 8; ++u) {
            s0 += el(v[u].x, off5, sAB);
            s1 += el(v[u].y, off5, sAB);
            s2 += el(v[u].z, off5, sAB);
            s3 += el(v[u].w, off5, sAB);
        }
    }
    for (int i = ntiles * TILE + blockIdx.x * 256 + t; i < n4; i += LGRID * 256) {
        float4 v = x4[i];
        s0 += el(v.x, off5, sAB); s1 += el(v.y, off5, sAB);
        s2 += el(v.z, off5, sAB); s3 += el(v.w, off5, sAB);
    }
    if (blockIdx.x == 0 && t == 0)               // scalar tail (none here)
        for (int i = n4 * 4; i < n; ++i) s0 += el(x[i], off5, sAB);

    double d = ((double)s0 + (double)s1) + ((double)s2 + (double)s3);
    #pragma unroll
    for (int dd = 32; dd; dd >>= 1) d += __shfl_down(d, dd);
    __shared__ double wsum[4];
    if ((t & 63) == 0) wsum[t >> 6] = d;
    __syncthreads();
    if (t == 0) {
        atomicAdd(acc, (wsum[0] + wsum[1]) + (wsum[2] + wsum[3]));
        __threadfence();
        if (atomicAdd(done, 1u) == gridDim.x - 1) {
            double total = atomicAdd(acc, 0.0);  // coherent read of final sum
            out[0] = (float)(-total * inv_n);    // rloss/n = -sum(log2)/n
        }
    }
}

// ---------------- launch ------------------------------------------------------

extern "C" void kernel_launch(void* const* d_in, const int* in_sizes, int n_in,
                              void* d_out, int out_size, void* d_ws, size_t ws_size,
                              hipStream_t stream) {
    const float* x = (const float*)d_in[0];
    int n = in_sizes[0];
    int n4 = n >> 2;
    float* out = (float*)d_out;

    uint8_t* ws = (uint8_t*)d_ws;
    uint32_t* slices  = (uint32_t*)ws;                    // 2048*256 u32 = 2 MB
    uint32_t* partial = (uint32_t*)(ws + 2097152);        // 256*256 u32 = 256 KB
    float2*   gAB     = (float2*)(ws + 2359296);          // 195 float2
    double*   acc     = (double*)(ws + 2361344);
    float*    off5    = (float*)(ws + 2361352);
    uint32_t* done    = (uint32_t*)(ws + 2361356);

    k_hist  <<<HGRID, 256, 0, stream>>>((const float4*)x, n4, x, n, slices);
    k_merge <<<MBLK,  256, 0, stream>>>(slices, partial);
    k_tables<<<1,     256, 0, stream>>>(partial, gAB, off5, acc, done, 1.0f / (float)n);
    k_loss  <<<LGRID, 256, 0, stream>>>((const float4*)x, n4, x, n, gAB, off5,
                                        acc, done, out, 1.0 / (double)n);
}

// Round 5
// 220.905 us; speedup vs baseline: 1.2726x; 1.2726x over previous
//
#include <hip/hip_runtime.h>
#include <stdint.h>

#define BPU    5
#define NBINS  200
#define GLEN   195   // NBINS - BPU
#define HLEN   196   // NBINS - BPU + 1
#define KH     256   // raw key-histogram bins; key = floor(x*5) + 128
#define NCOPY  16    // rotated LDS histogram copies (16 KB LDS -> 8 blocks/CU)
#define HGRID  2048  // k_hist grid
#define MBLK   256   // merge blocks
#define LGRID  2048  // k_loss grid
#define TILE   2048  // float4 per tile = 32 KB contiguous per block-tile

// ---------------- kernel 1: histogram into private per-block slices ----------
// Lane-rotated LDS copies: copy c stores key k at slot ((k + c) & 255);
// bank = (k + c) % 32 spreads same-bin lanes across banks.

__device__ inline void bump(float v, uint32_t* __restrict__ lh, int off, int cbase) {
    int b = __float2int_rd(v * 5.0f);            // floor(5x)
    b = min(max(b, -128), 127);                  // slot in [0,255]
    atomicAdd(&lh[cbase | ((b + off) & 255)], 1u);
}

__global__ __launch_bounds__(256) void k_hist(const float4* __restrict__ x4, int n4,
                                              const float* __restrict__ x, int n,
                                              uint32_t* __restrict__ slices) {
    __shared__ uint32_t lh[NCOPY * KH];          // 16 KB
    const int t = threadIdx.x;
    const int c = t & (NCOPY - 1);
    const int cbase = c << 8;
    const int off = 128 + c;                     // key offset + rotation
    for (int j = t; j < NCOPY * KH; j += 256) lh[j] = 0u;
    __syncthreads();

    const int ntiles = n4 / TILE;
    for (int tile = blockIdx.x; tile < ntiles; tile += HGRID) {
        const int base = tile * TILE + t;
        float4 v[8];
        #pragma unroll
        for (int u = 0; u < 8; ++u) v[u] = x4[base + (u << 8)];
        #pragma unroll
        for (int u = 0; u < 8; ++u) {
            bump(v[u].x, lh, off, cbase); bump(v[u].y, lh, off, cbase);
            bump(v[u].z, lh, off, cbase); bump(v[u].w, lh, off, cbase);
        }
    }
    for (int i = ntiles * TILE + blockIdx.x * 256 + t; i < n4; i += HGRID * 256) {
        float4 v = x4[i];
        bump(v.x, lh, off, cbase); bump(v.y, lh, off, cbase);
        bump(v.z, lh, off, cbase); bump(v.w, lh, off, cbase);
    }
    if (blockIdx.x == 0 && t == 0)               // scalar tail (none here)
        for (int i = n4 * 4; i < n; ++i) bump(x[i], lh, off, cbase);
    __syncthreads();

    // merge 16 rotated copies; plain coalesced store to this block's slice
    uint32_t s = 0;
    #pragma unroll 4
    for (int cc = 0; cc < NCOPY; ++cc) s += lh[(cc << 8) | ((t + cc) & 255)];
    slices[(blockIdx.x << 8) | t] = s;
}

// ---------------- kernel 2: 2048 slices -> 256 partials ----------------------

__global__ __launch_bounds__(256) void k_merge(const uint32_t* __restrict__ slices,
                                               uint32_t* __restrict__ partial) {
    const int t = threadIdx.x;
    const int b = blockIdx.x;
    const int per = HGRID / MBLK;                // 8
    uint32_t s = 0;
    #pragma unroll
    for (int j = 0; j < per; ++j) s += slices[((b * per + j) << 8) | t];
    partial[(b << 8) | t] = s;
}

// ---------------- kernel 3: final sum; derive vmin; build A/B table ----------

__global__ __launch_bounds__(256) void k_tables(const uint32_t* __restrict__ partial,
                                                float2* __restrict__ gAB,
                                                float*  __restrict__ off5_out,
                                                float inv_n) {
    __shared__ float cnt[KH];
    __shared__ float hist[NBINS];
    __shared__ float ha[HLEN];
    __shared__ int s_k0;
    const int t = threadIdx.x;
    uint32_t cv = 0;
    #pragma unroll 8
    for (int b = 0; b < MBLK; ++b) cv += partial[(b << 8) | t];
    cnt[t] = (float)cv;
    if (t == 0) s_k0 = KH;
    __syncthreads();
    if (cv) atomicMin(&s_k0, t);                 // lowest nonempty key
    __syncthreads();

    // floor(min) = floordiv(k0 - 128, 5)  (exact: bins align with integers)
    int a = s_k0 - 128;
    int fd = (a >= 0) ? (a / 5) : -((-a + 4) / 5);
    int ivmin = fd - 1;                          // vmin = floor(min) - 1
    int base = 128 + 5 * ivmin;                  // key of reference bin 0

    if (t < NBINS) {
        float h = 0.0f;
        if (t == 0) {
            for (int kk = 0; kk < KH && kk <= base; ++kk) h += cnt[kk];
        } else if (t == NBINS - 1) {
            int lo = base + (NBINS - 1); if (lo < 0) lo = 0;
            for (int kk = lo; kk < KH; ++kk) h += cnt[kk];
        } else {
            int kk = base + t;
            if (kk >= 0 && kk < KH) h = cnt[kk];
        }
        hist[t] = h * inv_n;
    }
    __syncthreads();

    // inclusive Hillis-Steele scan over hist[0..199]
    for (int offs = 1; offs < NBINS; offs <<= 1) {
        float v = 0.0f;
        if (t < NBINS && t >= offs) v = hist[t - offs];
        __syncthreads();
        if (t < NBINS && t >= offs) hist[t] += v;
        __syncthreads();
    }

    if (t < HLEN) {
        float c_lo = (t == 0) ? 0.0f : hist[t - 1];
        ha[t] = hist[t + BPU - 1] - c_lo;        // c[t+5] - c[t]
    }
    __syncthreads();

    float vmn = (float)ivmin + 0.5f;             // vmin_new
    if (t < GLEN) {
        float A = (ha[t + 1] - ha[t]) * 5.0f;    // g[t]
        float left = vmn + (float)t * 0.2f;
        float B = ha[t] - left * A + 1e-8f;      // nloss = fma(x, A, B)
        gAB[t] = make_float2(A, B);
    }
    if (t == 0) *off5_out = vmn * 5.0f;
}

// ---------------- kernel 4: per-element loss -> per-block partial (no atomics)

__device__ inline float el(float v, float off5, const float2* __restrict__ sAB) {
    float fi = fminf(fmaxf(fmaf(v, 5.0f, -off5), 0.0f), (float)(GLEN - 1));
    float2 ab = sAB[(int)fi];                    // ds_read_b64 gather
    return __log2f(fmaf(v, ab.x, ab.y));
}

__global__ __launch_bounds__(256) void k_loss(const float4* __restrict__ x4, int n4,
                                              const float* __restrict__ x, int n,
                                              const float2* __restrict__ gAB,
                                              const float*  __restrict__ off5_p,
                                              double* __restrict__ pdbl) {
    __shared__ float2 sAB[GLEN];
    const int t = threadIdx.x;
    if (t < GLEN) sAB[t] = gAB[t];
    const float off5 = *off5_p;
    __syncthreads();

    float s0 = 0.f, s1 = 0.f, s2 = 0.f, s3 = 0.f;
    const int ntiles = n4 / TILE;
    for (int tile = blockIdx.x; tile < ntiles; tile += LGRID) {
        const int base = tile * TILE + t;
        float4 v[8];
        #pragma unroll
        for (int u = 0; u < 8; ++u) v[u] = x4[base + (u << 8)];
        #pragma unroll
        for (int u = 0; u < 8; ++u) {
            s0 += el(v[u].x, off5, sAB);
            s1 += el(v[u].y, off5, sAB);
            s2 += el(v[u].z, off5, sAB);
            s3 += el(v[u].w, off5, sAB);
        }
    }
    for (int i = ntiles * TILE + blockIdx.x * 256 + t; i < n4; i += LGRID * 256) {
        float4 v = x4[i];
        s0 += el(v.x, off5, sAB); s1 += el(v.y, off5, sAB);
        s2 += el(v.z, off5, sAB); s3 += el(v.w, off5, sAB);
    }
    if (blockIdx.x == 0 && t == 0)               // scalar tail (none here)
        for (int i = n4 * 4; i < n; ++i) s0 += el(x[i], off5, sAB);

    double d = ((double)s0 + (double)s1) + ((double)s2 + (double)s3);
    #pragma unroll
    for (int dd = 32; dd; dd >>= 1) d += __shfl_down(d, dd);
    __shared__ double wsum[4];
    if ((t & 63) == 0) wsum[t >> 6] = d;
    __syncthreads();
    if (t == 0) pdbl[blockIdx.x] = (wsum[0] + wsum[1]) + (wsum[2] + wsum[3]);
}

// ---------------- kernel 5: reduce 2048 per-block partials -> output ---------

__global__ __launch_bounds__(256) void k_final(const double* __restrict__ pdbl,
                                               float* __restrict__ out, double inv_n) {
    const int t = threadIdx.x;
    double s = 0.0;
    #pragma unroll
    for (int j = 0; j < LGRID / 256; ++j) s += pdbl[t + (j << 8)];
    #pragma unroll
    for (int d = 32; d; d >>= 1) s += __shfl_down(s, d);
    __shared__ double wsum[4];
    if ((t & 63) == 0) wsum[t >> 6] = s;
    __syncthreads();
    if (t == 0)
        out[0] = (float)(-((wsum[0] + wsum[1]) + (wsum[2] + wsum[3])) * inv_n);
}

// ---------------- launch ------------------------------------------------------

extern "C" void kernel_launch(void* const* d_in, const int* in_sizes, int n_in,
                              void* d_out, int out_size, void* d_ws, size_t ws_size,
                              hipStream_t stream) {
    const float* x = (const float*)d_in[0];
    int n = in_sizes[0];
    int n4 = n >> 2;
    float* out = (float*)d_out;

    uint8_t* ws = (uint8_t*)d_ws;
    uint32_t* slices  = (uint32_t*)ws;                    // 2048*256 u32 = 2 MB
    uint32_t* partial = (uint32_t*)(ws + 2097152);        // 256*256 u32 = 256 KB
    float2*   gAB     = (float2*)(ws + 2359296);          // 195 float2
    float*    off5    = (float*)(ws + 2361344);
    double*   pdbl    = (double*)(ws + 2361352);          // 2048 doubles = 16 KB

    k_hist  <<<HGRID, 256, 0, stream>>>((const float4*)x, n4, x, n, slices);
    k_merge <<<MBLK,  256, 0, stream>>>(slices, partial);
    k_tables<<<1,     256, 0, stream>>>(partial, gAB, off5, 1.0f / (float)n);
    k_loss  <<<LGRID, 256, 0, stream>>>((const float4*)x, n4, x, n, gAB, off5, pdbl);
    k_final <<<1,     256, 0, stream>>>(pdbl, out, 1.0 / (double)n);
}